// Round 1
// baseline (744.783 us; speedup 1.0000x reference)
//
#include <hip/hip_runtime.h>
#include <hip/hip_bf16.h>

// Problem constants (B,C,H,W)=(8,384,32,32), GROUPS=3, HEADS=12, KSIZE=5
static constexpr int B = 8;
static constexpr int C = 384;
static constexpr int H = 32;
static constexpr int W = 32;
static constexpr int N = 1024;      // H*W
static constexpr int G = 3;
static constexpr int Cg = 128;      // C/G
static constexpr int HEADS = 12;
static constexpr int HC = 32;       // C/HEADS
static constexpr int BG = 24;       // B*G
static constexpr float SCALE = 0.17677669529663687f; // hc^-0.5

// ---------------------------------------------------------------------------
// Generic per-batch SGEMM: Y[b][o][n] = sum_c Wt[o][c]*X[b][c][n] + bias[o] (+res)
// Tile 64(o) x 64(n), K-tile 16, 4x4 per thread, 256 threads.
// ---------------------------------------------------------------------------
template<bool RES>
__global__ __launch_bounds__(256) void gemm384(const float* __restrict__ Wt,
                                               const float* __restrict__ bias,
                                               const float* __restrict__ X,
                                               const float* __restrict__ res,
                                               float* __restrict__ Y)
{
    __shared__ float sA[64][17];   // [o][k], pad 17 to avoid write conflicts
    __shared__ float sB[16][64];   // [k][n]
    const int tid = threadIdx.x;
    const int n0 = blockIdx.x * 64;
    const int o0 = blockIdx.y * 64;
    const int b  = blockIdx.z;
    const float* Xb = X + (size_t)b * C * N;
    const int tn = tid & 15, to = tid >> 4;
    float acc[4][4] = {};
    for (int c0 = 0; c0 < C; c0 += 16) {
        {
            int kk = tid & 15, oo = tid >> 4;
            #pragma unroll
            for (int i = 0; i < 4; ++i)
                sA[oo + 16*i][kk] = Wt[(size_t)(o0 + oo + 16*i)*C + c0 + kk];
        }
        {
            int col = tid & 63, row = tid >> 6;
            #pragma unroll
            for (int i = 0; i < 4; ++i)
                sB[row + 4*i][col] = Xb[(size_t)(c0 + row + 4*i)*N + n0 + col];
        }
        __syncthreads();
        #pragma unroll
        for (int kk = 0; kk < 16; ++kk) {
            float4 b4 = *(const float4*)&sB[kk][tn*4];
            float bb[4] = {b4.x, b4.y, b4.z, b4.w};
            float aa[4];
            #pragma unroll
            for (int i = 0; i < 4; ++i) aa[i] = sA[to*4 + i][kk];
            #pragma unroll
            for (int i = 0; i < 4; ++i)
                #pragma unroll
                for (int j = 0; j < 4; ++j)
                    acc[i][j] += aa[i] * bb[j];
        }
        __syncthreads();
    }
    #pragma unroll
    for (int i = 0; i < 4; ++i) {
        int o = o0 + to*4 + i;
        float bz = bias[o];
        size_t idx = (size_t)b*C*N + (size_t)o*N + n0 + tn*4;
        float4 v = make_float4(acc[i][0]+bz, acc[i][1]+bz, acc[i][2]+bz, acc[i][3]+bz);
        if (RES) {
            float4 r4 = *(const float4*)&res[idx];
            v.x += r4.x; v.y += r4.y; v.z += r4.z; v.w += r4.w;
        }
        *(float4*)&Y[idx] = v;
    }
}

// ---------------------------------------------------------------------------
// Depthwise 5x5 conv (SAME, zero pad) + bias + tanh-approx GELU.
// grid (N/256, Cg, BG)
// ---------------------------------------------------------------------------
__global__ __launch_bounds__(256) void dwconv_gelu(const float* __restrict__ q,
                                                   const float* __restrict__ wdw,
                                                   const float* __restrict__ bdw,
                                                   float* __restrict__ t)
{
    const int n = blockIdx.x * 256 + threadIdx.x;
    const int c = blockIdx.y, bg = blockIdx.z;
    const int y = n >> 5, x = n & 31;
    const float* qc = q + ((size_t)bg*Cg + c)*N;
    const float* wc = wdw + c*25;
    float acc = bdw[c];
    #pragma unroll
    for (int ky = 0; ky < 5; ++ky) {
        int yy = y + ky - 2;
        if (yy < 0 || yy >= H) continue;
        #pragma unroll
        for (int kx = 0; kx < 5; ++kx) {
            int xx = x + kx - 2;
            if (xx < 0 || xx >= W) continue;
            acc += wc[ky*5 + kx] * qc[yy*W + xx];
        }
    }
    float u = acc;
    float g = 0.5f*u*(1.0f + tanhf(0.7978845608028654f*(u + 0.044715f*u*u*u)));
    t[((size_t)bg*Cg + c)*N + n] = g;
}

// ---------------------------------------------------------------------------
// Pointwise conv (2 x Cg) + tanh -> clipped grid -> bilinear coords.
// One thread per (bg, n). Stores float4(x0, y0, wx1, wy1).
// ---------------------------------------------------------------------------
__global__ __launch_bounds__(256) void offset_grid(const float* __restrict__ t,
                                                   const float* __restrict__ wpw,
                                                   const float* __restrict__ bpw,
                                                   float* __restrict__ coords)
{
    const int gid = blockIdx.x * 256 + threadIdx.x; // BG*N = 24576
    const int bg = gid >> 10, n = gid & 1023;
    const float* tb = t + (size_t)bg*Cg*N + n;
    float a0 = bpw[0], a1 = bpw[1];
    for (int c = 0; c < Cg; ++c) {
        float tv = tb[(size_t)c*N];
        a0 += wpw[c] * tv;
        a1 += wpw[Cg + c] * tv;
    }
    const int x = n & 31, y = n >> 5;
    float dx = tanhf(a0) * (2.0f / W);
    float dy = tanhf(a1) * (2.0f / H);
    float rx = (x + 0.5f) / W * 2.0f - 1.0f;
    float ry = (y + 0.5f) / H * 2.0f - 1.0f;
    float px = fminf(fmaxf(rx + dx, -1.0f), 1.0f);
    float py = fminf(fmaxf(ry + dy, -1.0f), 1.0f);
    float gx = (px + 1.0f) * 0.5f * (W - 1);
    float gy = (py + 1.0f) * 0.5f * (H - 1);
    float x0 = floorf(gx), y0 = floorf(gy);
    float wx1 = gx - x0, wy1 = gy - y0;
    x0 = fminf(fmaxf(x0, 0.0f), (float)(W - 1));
    y0 = fminf(fmaxf(y0, 0.0f), (float)(H - 1));
    ((float4*)coords)[gid] = make_float4(x0, y0, wx1, wy1);
}

// ---------------------------------------------------------------------------
// Bilinear gather of x2 at deformed coords. grid (N/256, Cg, BG)
// ---------------------------------------------------------------------------
__global__ __launch_bounds__(256) void bilin_sample(const float* __restrict__ x2,
                                                    const float* __restrict__ coords,
                                                    float* __restrict__ sampled)
{
    const int n = blockIdx.x * 256 + threadIdx.x;
    const int c = blockIdx.y, bg = blockIdx.z;
    float4 c4 = ((const float4*)coords)[bg*N + n];
    int x0 = (int)c4.x, y0 = (int)c4.y;
    float wx1 = c4.z, wy1 = c4.w;
    int x1 = min(x0 + 1, W - 1), y1 = min(y0 + 1, H - 1);
    float wx0 = 1.0f - wx1, wy0 = 1.0f - wy1;
    const float* img = x2 + ((size_t)bg*Cg + c)*N;
    float v00 = img[y0*W + x0], v01 = img[y0*W + x1];
    float v10 = img[y1*W + x0], v11 = img[y1*W + x1];
    sampled[((size_t)bg*Cg + c)*N + n] =
        wy0*(wx0*v00 + wx1*v01) + wy1*(wx0*v10 + wx1*v11);
}

// ---------------------------------------------------------------------------
// QK^T (K=32) + row softmax, attn written once to d_out.
// Block: 8 rows x full 1024 cols. Each wave owns rows (w, w+4) in registers.
// grid (N/8, B*HEADS)
// ---------------------------------------------------------------------------
__global__ __launch_bounds__(256) void attn_softmax(const float* __restrict__ q,
                                                    const float* __restrict__ k,
                                                    float* __restrict__ attn)
{
    __shared__ float ks[32][64];
    __shared__ float qs[32][8];
    const int tid = threadIdx.x;
    const int n0 = blockIdx.x * 8;
    const int bh = blockIdx.y;
    const int b = bh / HEADS, h = bh - b*HEADS;
    const float* qb = q + ((size_t)b*C + h*HC)*N;
    const float* kb = k + ((size_t)b*C + h*HC)*N;
    {
        int cl = tid >> 3, r = tid & 7;
        qs[cl][r] = qb[(size_t)cl*N + n0 + r];
    }
    __syncthreads();
    const int mm = tid & 63, r0 = tid >> 6;
    float qr0[32], qr1[32];
    #pragma unroll
    for (int cl = 0; cl < 32; ++cl) { qr0[cl] = qs[cl][r0]; qr1[cl] = qs[cl][r0 + 4]; }
    float acc[2][16];
    #pragma unroll
    for (int mt = 0; mt < 16; ++mt) {
        __syncthreads();
        {
            int col = tid & 63, row = tid >> 6;
            #pragma unroll
            for (int i = 0; i < 8; ++i)
                ks[row + 4*i][col] = kb[(size_t)(row + 4*i)*N + mt*64 + col];
        }
        __syncthreads();
        float a0 = 0.f, a1 = 0.f;
        #pragma unroll
        for (int cl = 0; cl < 32; ++cl) {
            float kv = ks[cl][mm];
            a0 += qr0[cl] * kv;
            a1 += qr1[cl] * kv;
        }
        acc[0][mt] = a0 * SCALE;
        acc[1][mt] = a1 * SCALE;
    }
    // softmax over each wave-owned row (cols = mt*64 + lane)
    #pragma unroll
    for (int rr = 0; rr < 2; ++rr) {
        float mx = -3.4e38f;
        #pragma unroll
        for (int mt = 0; mt < 16; ++mt) mx = fmaxf(mx, acc[rr][mt]);
        #pragma unroll
        for (int s = 32; s; s >>= 1) mx = fmaxf(mx, __shfl_xor(mx, s, 64));
        float sum = 0.f;
        #pragma unroll
        for (int mt = 0; mt < 16; ++mt) { acc[rr][mt] = __expf(acc[rr][mt] - mx); sum += acc[rr][mt]; }
        #pragma unroll
        for (int s = 32; s; s >>= 1) sum += __shfl_xor(sum, s, 64);
        float inv = 1.0f / sum;
        size_t rowbase = ((size_t)bh*N + n0 + r0 + rr*4) * (size_t)N;
        #pragma unroll
        for (int mt = 0; mt < 16; ++mt)
            attn[rowbase + mt*64 + mm] = acc[rr][mt] * inv;
    }
}

// ---------------------------------------------------------------------------
// out[b][h*32+cl][n] = sum_m attn[bh][n][m] * v[b][h*32+cl][m]
// K=1024 in 64-chunks; transposed LDS tiles for conflict-free float4/float2 reads.
// grid (N/64, B*HEADS)
// ---------------------------------------------------------------------------
__global__ __launch_bounds__(256) void out_gemm(const float* __restrict__ attn,
                                                const float* __restrict__ v,
                                                float* __restrict__ outb)
{
    __shared__ float a_s[64][68];  // [m][n]
    __shared__ float v_s[64][34];  // [m][cl]
    const int tid = threadIdx.x;
    const int n0 = blockIdx.x * 64;
    const int bh = blockIdx.y;
    const int b = bh / HEADS, h = bh - b*HEADS;
    const float* ab = attn + (size_t)bh * N * N;
    const float* vb = v + ((size_t)b*C + h*HC)*N;
    const int tn = tid & 15, tc = tid >> 4;
    float acc[2][4] = {};
    for (int m0 = 0; m0 < N; m0 += 64) {
        __syncthreads();
        {
            int mmc = tid & 63, base = tid >> 6;
            #pragma unroll
            for (int i = 0; i < 16; ++i)
                a_s[mmc][base + 4*i] = ab[(size_t)(n0 + base + 4*i)*N + m0 + mmc];
            #pragma unroll
            for (int i = 0; i < 8; ++i)
                v_s[mmc][base + 4*i] = vb[(size_t)(base + 4*i)*N + m0 + mmc];
        }
        __syncthreads();
        #pragma unroll 8
        for (int mm = 0; mm < 64; ++mm) {
            float4 a4 = *(const float4*)&a_s[mm][4*tn];
            float2 v2 = *(const float2*)&v_s[mm][2*tc];
            acc[0][0] += v2.x * a4.x; acc[0][1] += v2.x * a4.y;
            acc[0][2] += v2.x * a4.z; acc[0][3] += v2.x * a4.w;
            acc[1][0] += v2.y * a4.x; acc[1][1] += v2.y * a4.y;
            acc[1][2] += v2.y * a4.z; acc[1][3] += v2.y * a4.w;
        }
    }
    #pragma unroll
    for (int i = 0; i < 2; ++i) {
        int cl = 2*tc + i;
        size_t idx = ((size_t)b*C + h*HC + cl)*N + n0 + 4*tn;
        *(float4*)&outb[idx] = make_float4(acc[i][0], acc[i][1], acc[i][2], acc[i][3]);
    }
}

// ---------------------------------------------------------------------------
extern "C" void kernel_launch(void* const* d_in, const int* in_sizes, int n_in,
                              void* d_out, int out_size, void* d_ws, size_t ws_size,
                              hipStream_t stream)
{
    const float* x1  = (const float*)d_in[0];
    const float* x2  = (const float*)d_in[1];
    const float* wq  = (const float*)d_in[2];
    const float* bq  = (const float*)d_in[3];
    const float* wdw = (const float*)d_in[4];
    const float* bdw = (const float*)d_in[5];
    const float* wpw = (const float*)d_in[6];
    const float* bpw = (const float*)d_in[7];
    const float* wk  = (const float*)d_in[8];
    const float* bk  = (const float*)d_in[9];
    const float* wv  = (const float*)d_in[10];
    const float* bv  = (const float*)d_in[11];
    const float* wo  = (const float*)d_in[12];
    const float* bo  = (const float*)d_in[13];

    const size_t PLANE = (size_t)B * C * N;     // 3,145,728 floats
    float* ws      = (float*)d_ws;
    float* qbuf    = ws;
    float* tbuf    = ws + PLANE;                // reused as out-buffer later
    float* sampled = ws + 2*PLANE;
    float* kbuf    = ws + 3*PLANE;
    float* vbuf    = ws + 4*PLANE;
    float* coords  = ws + 5*PLANE;              // BG*N float4 = 98,304 floats

    float* ybuf = (float*)d_out;                // (B,C,H,W)
    float* attn = (float*)d_out + PLANE;        // (B,HEADS,N,N)

    gemm384<false><<<dim3(16, 6, 8), 256, 0, stream>>>(wq, bq, x1, nullptr, qbuf);
    dwconv_gelu<<<dim3(4, Cg, BG), 256, 0, stream>>>(qbuf, wdw, bdw, tbuf);
    offset_grid<<<dim3(96), 256, 0, stream>>>(tbuf, wpw, bpw, coords);
    bilin_sample<<<dim3(4, Cg, BG), 256, 0, stream>>>(x2, coords, sampled);
    gemm384<false><<<dim3(16, 6, 8), 256, 0, stream>>>(wk, bk, sampled, nullptr, kbuf);
    gemm384<false><<<dim3(16, 6, 8), 256, 0, stream>>>(wv, bv, sampled, nullptr, vbuf);
    attn_softmax<<<dim3(128, 96), 256, 0, stream>>>(qbuf, kbuf, attn);
    out_gemm<<<dim3(16, 96), 256, 0, stream>>>(attn, vbuf, tbuf);
    gemm384<true><<<dim3(16, 6, 8), 256, 0, stream>>>(wo, bo, tbuf, x1, ybuf);
}

// Round 2
// 338.009 us; speedup vs baseline: 2.2034x; 2.2034x over previous
//
#include <hip/hip_runtime.h>
#include <hip/hip_bf16.h>

static constexpr int B = 8;
static constexpr int C = 384;
static constexpr int H = 32;
static constexpr int W = 32;
static constexpr int N = 1024;      // H*W
static constexpr int Cg = 128;      // C/G
static constexpr int HEADS = 12;
static constexpr int BG = 24;       // B*G
static constexpr float SCALE = 0.17677669529663687f; // hc^-0.5

typedef short bf16x8 __attribute__((ext_vector_type(8)));
typedef float f32x4 __attribute__((ext_vector_type(4)));

__device__ __forceinline__ unsigned short bf16_bits(float x) {
    __hip_bfloat16 h = __float2bfloat16(x);
    return __builtin_bit_cast(unsigned short, h);
}

// ---------------------------------------------------------------------------
// Generic per-batch SGEMM: Y[b][o][n] = sum_c Wt[o][c]*X[b][c][n] + bias[o] (+res)
// ---------------------------------------------------------------------------
template<bool RES>
__global__ __launch_bounds__(256) void gemm384(const float* __restrict__ Wt,
                                               const float* __restrict__ bias,
                                               const float* __restrict__ X,
                                               const float* __restrict__ res,
                                               float* __restrict__ Y)
{
    __shared__ float sA[64][17];
    __shared__ float sB[16][64];
    const int tid = threadIdx.x;
    const int n0 = blockIdx.x * 64;
    const int o0 = blockIdx.y * 64;
    const int b  = blockIdx.z;
    const float* Xb = X + (size_t)b * C * N;
    const int tn = tid & 15, to = tid >> 4;
    float acc[4][4] = {};
    for (int c0 = 0; c0 < C; c0 += 16) {
        {
            int kk = tid & 15, oo = tid >> 4;
            #pragma unroll
            for (int i = 0; i < 4; ++i)
                sA[oo + 16*i][kk] = Wt[(size_t)(o0 + oo + 16*i)*C + c0 + kk];
        }
        {
            int col = tid & 63, row = tid >> 6;
            #pragma unroll
            for (int i = 0; i < 4; ++i)
                sB[row + 4*i][col] = Xb[(size_t)(c0 + row + 4*i)*N + n0 + col];
        }
        __syncthreads();
        #pragma unroll
        for (int kk = 0; kk < 16; ++kk) {
            float4 b4 = *(const float4*)&sB[kk][tn*4];
            float bb[4] = {b4.x, b4.y, b4.z, b4.w};
            float aa[4];
            #pragma unroll
            for (int i = 0; i < 4; ++i) aa[i] = sA[to*4 + i][kk];
            #pragma unroll
            for (int i = 0; i < 4; ++i)
                #pragma unroll
                for (int j = 0; j < 4; ++j)
                    acc[i][j] += aa[i] * bb[j];
        }
        __syncthreads();
    }
    #pragma unroll
    for (int i = 0; i < 4; ++i) {
        int o = o0 + to*4 + i;
        float bz = bias[o];
        size_t idx = (size_t)b*C*N + (size_t)o*N + n0 + tn*4;
        float4 v = make_float4(acc[i][0]+bz, acc[i][1]+bz, acc[i][2]+bz, acc[i][3]+bz);
        if (RES) {
            float4 r4 = *(const float4*)&res[idx];
            v.x += r4.x; v.y += r4.y; v.z += r4.z; v.w += r4.w;
        }
        *(float4*)&Y[idx] = v;
    }
}

// ---------------------------------------------------------------------------
// Depthwise 5x5 conv (SAME) + bias + tanh GELU
// ---------------------------------------------------------------------------
__global__ __launch_bounds__(256) void dwconv_gelu(const float* __restrict__ q,
                                                   const float* __restrict__ wdw,
                                                   const float* __restrict__ bdw,
                                                   float* __restrict__ t)
{
    const int n = blockIdx.x * 256 + threadIdx.x;
    const int c = blockIdx.y, bg = blockIdx.z;
    const int y = n >> 5, x = n & 31;
    const float* qc = q + ((size_t)bg*Cg + c)*N;
    const float* wc = wdw + c*25;
    float acc = bdw[c];
    #pragma unroll
    for (int ky = 0; ky < 5; ++ky) {
        int yy = y + ky - 2;
        if (yy < 0 || yy >= H) continue;
        #pragma unroll
        for (int kx = 0; kx < 5; ++kx) {
            int xx = x + kx - 2;
            if (xx < 0 || xx >= W) continue;
            acc += wc[ky*5 + kx] * qc[yy*W + xx];
        }
    }
    float u = acc;
    float g = 0.5f*u*(1.0f + tanhf(0.7978845608028654f*(u + 0.044715f*u*u*u)));
    t[((size_t)bg*Cg + c)*N + n] = g;
}

// ---------------------------------------------------------------------------
// Pointwise conv (2 x Cg) + tanh -> clipped grid -> bilinear coords.
// Block: 64 n positions x 4 c-quarters reduced in LDS. grid(384)
// ---------------------------------------------------------------------------
__global__ __launch_bounds__(256) void offset_grid(const float* __restrict__ t,
                                                   const float* __restrict__ wpw,
                                                   const float* __restrict__ bpw,
                                                   float* __restrict__ coords)
{
    __shared__ float r0[4][64], r1[4][64];
    const int bx = blockIdx.x;
    const int bg = bx >> 4, n0 = (bx & 15) * 64;
    const int nl = threadIdx.x & 63, cq = threadIdx.x >> 6;
    const float* tb = t + ((size_t)bg*Cg + cq*32)*N + n0 + nl;
    float a0 = 0.f, a1 = 0.f;
    #pragma unroll 8
    for (int i = 0; i < 32; ++i) {
        float tv = tb[(size_t)i*N];
        a0 += wpw[cq*32 + i] * tv;
        a1 += wpw[Cg + cq*32 + i] * tv;
    }
    r0[cq][nl] = a0; r1[cq][nl] = a1;
    __syncthreads();
    if (threadIdx.x < 64) {
        int n = n0 + nl;
        a0 = bpw[0] + r0[0][nl] + r0[1][nl] + r0[2][nl] + r0[3][nl];
        a1 = bpw[1] + r1[0][nl] + r1[1][nl] + r1[2][nl] + r1[3][nl];
        const int x = n & 31, y = n >> 5;
        float dx = tanhf(a0) * (2.0f / W);
        float dy = tanhf(a1) * (2.0f / H);
        float rx = (x + 0.5f) / W * 2.0f - 1.0f;
        float ry = (y + 0.5f) / H * 2.0f - 1.0f;
        float px = fminf(fmaxf(rx + dx, -1.0f), 1.0f);
        float py = fminf(fmaxf(ry + dy, -1.0f), 1.0f);
        float gx = (px + 1.0f) * 0.5f * (W - 1);
        float gy = (py + 1.0f) * 0.5f * (H - 1);
        float x0 = floorf(gx), y0 = floorf(gy);
        float wx1 = gx - x0, wy1 = gy - y0;
        x0 = fminf(fmaxf(x0, 0.0f), (float)(W - 1));
        y0 = fminf(fmaxf(y0, 0.0f), (float)(H - 1));
        ((float4*)coords)[bg*N + n] = make_float4(x0, y0, wx1, wy1);
    }
}

// ---------------------------------------------------------------------------
// Bilinear gather of x2. grid (4, 128, 24)
// ---------------------------------------------------------------------------
__global__ __launch_bounds__(256) void bilin_sample(const float* __restrict__ x2,
                                                    const float* __restrict__ coords,
                                                    float* __restrict__ sampled)
{
    const int n = blockIdx.x * 256 + threadIdx.x;
    const int c = blockIdx.y, bg = blockIdx.z;
    float4 c4 = ((const float4*)coords)[bg*N + n];
    int x0 = (int)c4.x, y0 = (int)c4.y;
    float wx1 = c4.z, wy1 = c4.w;
    int x1 = min(x0 + 1, W - 1), y1 = min(y0 + 1, H - 1);
    float wx0 = 1.0f - wx1, wy0 = 1.0f - wy1;
    const float* img = x2 + ((size_t)bg*Cg + c)*N;
    float v00 = img[y0*W + x0], v01 = img[y0*W + x1];
    float v10 = img[y1*W + x0], v11 = img[y1*W + x1];
    sampled[((size_t)bg*Cg + c)*N + n] =
        wy0*(wx0*v00 + wx1*v01) + wy1*(wx0*v10 + wx1*v11);
}

// ---------------------------------------------------------------------------
// Transpose+convert: src [bh][32c][1024n] fp32 -> dst [bh][1024n][32c] bf16 (*scale)
// grid (8 n-chunks, 96 bh)
// ---------------------------------------------------------------------------
__global__ __launch_bounds__(256) void xpose_bf16(const float* __restrict__ src,
                                                  unsigned int* __restrict__ dst,
                                                  float scale)
{
    __shared__ float tile[32][129];
    const int tid = threadIdx.x;
    const int n0 = blockIdx.x * 128;
    const int bh = blockIdx.y;
    const float* sb = src + (size_t)bh * 32 * N;
    #pragma unroll
    for (int i = 0; i < 16; ++i) {
        int idx = tid + i*256;
        int c = idx >> 7, n = idx & 127;
        tile[c][n] = sb[(size_t)c*N + n0 + n];
    }
    __syncthreads();
    #pragma unroll
    for (int i = 0; i < 8; ++i) {
        int idx = tid + i*256;
        int n = idx >> 4, cp = idx & 15;
        float a = tile[2*cp][n] * scale;
        float b = tile[2*cp + 1][n] * scale;
        unsigned int u = (unsigned int)bf16_bits(a) | ((unsigned int)bf16_bits(b) << 16);
        dst[((size_t)bh*N + n0 + n)*16 + cp] = u;
    }
}

// ---------------------------------------------------------------------------
// Plain fp32 -> bf16 convert (for V). grid(1536), 8 elems/thread
// ---------------------------------------------------------------------------
__global__ __launch_bounds__(256) void conv_bf16(const float* __restrict__ src,
                                                 unsigned short* __restrict__ dst)
{
    const int gid = blockIdx.x * 256 + threadIdx.x;
    const float4* p = (const float4*)(src + (size_t)gid * 8);
    float4 f0 = p[0], f1 = p[1];
    uint4 u;
    u.x = (unsigned)bf16_bits(f0.x) | ((unsigned)bf16_bits(f0.y) << 16);
    u.y = (unsigned)bf16_bits(f0.z) | ((unsigned)bf16_bits(f0.w) << 16);
    u.z = (unsigned)bf16_bits(f1.x) | ((unsigned)bf16_bits(f1.y) << 16);
    u.w = (unsigned)bf16_bits(f1.z) | ((unsigned)bf16_bits(f1.w) << 16);
    ((uint4*)dst)[gid] = u;
}

// ---------------------------------------------------------------------------
// Fused attention: QK^T (MFMA) + two-pass softmax + attn write + PV (MFMA).
// Block: 256 thr = 4 waves; one (b,h); 64 query rows (16/wave).
// qT: [bh][1024n][32c] bf16 (pre-scaled), kT: [bh][1024m][32c] bf16,
// v16: [b][384c][1024m] bf16. attn: fp32 [bh][1024][1024]. obuf: fp32 [b][384][1024].
// grid (16, 96)
// ---------------------------------------------------------------------------
__global__ __launch_bounds__(256) void attn_fused(const unsigned short* __restrict__ qT,
                                                  const unsigned short* __restrict__ kT,
                                                  const unsigned short* __restrict__ v16,
                                                  float* __restrict__ attn,
                                                  float* __restrict__ obuf)
{
    __shared__ __align__(16) unsigned short qs[64*40];     //  5,120 B
    __shared__ __align__(16) unsigned short ks[256*40];    // 20,480 B
    __shared__ __align__(16) unsigned short vs[32*264];    // 16,896 B
    __shared__ __align__(16) unsigned short ps[4][16*264]; // 33,792 B

    const int tid = threadIdx.x;
    const int lane = tid & 63, w = tid >> 6;
    const int l15 = lane & 15, lq = lane >> 4;
    const int nb = blockIdx.x, bh = blockIdx.y;
    const int b = bh / HEADS, h = bh - b*HEADS;

    const unsigned short* qg = qT + ((size_t)bh*N + nb*64)*32;
    const unsigned short* kg = kT + (size_t)bh*N*32;
    const unsigned short* vg = v16 + ((size_t)b*C + h*32)*N;

    // stage Q tile (64 rows x 32c) into padded LDS
    {
        int r = tid >> 2, c8 = (tid & 3) * 8;
        *(bf16x8*)(qs + r*40 + c8) = *(const bf16x8*)(qg + r*32 + c8);
    }
    __syncthreads();
    const bf16x8 afrag = *(const bf16x8*)(qs + (w*16 + l15)*40 + lq*8);

    float mx[4] = {-3.4e38f, -3.4e38f, -3.4e38f, -3.4e38f};
    float sm[4] = {0.f, 0.f, 0.f, 0.f};
    f32x4 s[16];
    const f32x4 zero = {0.f, 0.f, 0.f, 0.f};

    // ------------------ PASS 1: stats ------------------
    for (int ch = 0; ch < 4; ++ch) {
        __syncthreads();
        #pragma unroll
        for (int i = 0; i < 4; ++i) {
            int m = i*64 + (tid >> 2), c8 = (tid & 3) * 8;
            *(bf16x8*)(ks + m*40 + c8) = *(const bf16x8*)(kg + ((size_t)ch*256 + m)*32 + c8);
        }
        __syncthreads();
        #pragma unroll
        for (int t = 0; t < 16; ++t) {
            bf16x8 bfrag = *(const bf16x8*)(ks + (16*t + l15)*40 + lq*8);
            s[t] = __builtin_amdgcn_mfma_f32_16x16x32_bf16(afrag, bfrag, zero, 0, 0, 0);
        }
        #pragma unroll
        for (int r = 0; r < 4; ++r) {
            float cm = s[0][r];
            #pragma unroll
            for (int t = 1; t < 16; ++t) cm = fmaxf(cm, s[t][r]);
            cm = fmaxf(cm, __shfl_xor(cm, 1));
            cm = fmaxf(cm, __shfl_xor(cm, 2));
            cm = fmaxf(cm, __shfl_xor(cm, 4));
            cm = fmaxf(cm, __shfl_xor(cm, 8));
            float nm = fmaxf(mx[r], cm);
            float corr = __expf(mx[r] - nm);
            float es = 0.f;
            #pragma unroll
            for (int t = 0; t < 16; ++t) es += __expf(s[t][r] - nm);
            es += __shfl_xor(es, 1);
            es += __shfl_xor(es, 2);
            es += __shfl_xor(es, 4);
            es += __shfl_xor(es, 8);
            sm[r] = sm[r]*corr + es;
            mx[r] = nm;
        }
    }
    float inv[4];
    #pragma unroll
    for (int r = 0; r < 4; ++r) inv[r] = 1.0f / sm[r];

    // ------------------ PASS 2: P write + PV ------------------
    f32x4 outf[2] = {zero, zero};
    unsigned short* pw = ps[w];
    float* arow = attn + ((size_t)bh*N + (size_t)nb*64 + w*16)*N;

    for (int ch = 0; ch < 4; ++ch) {
        __syncthreads();
        #pragma unroll
        for (int i = 0; i < 4; ++i) {
            int m = i*64 + (tid >> 2), c8 = (tid & 3) * 8;
            *(bf16x8*)(ks + m*40 + c8) = *(const bf16x8*)(kg + ((size_t)ch*256 + m)*32 + c8);
        }
        #pragma unroll
        for (int i = 0; i < 4; ++i) {
            int u = tid + i*256;
            int cl = u >> 5, g = u & 31;
            *(bf16x8*)(vs + cl*264 + g*8) = *(const bf16x8*)(vg + (size_t)cl*N + ch*256 + g*8);
        }
        __syncthreads();
        #pragma unroll
        for (int t = 0; t < 16; ++t) {
            bf16x8 bfrag = *(const bf16x8*)(ks + (16*t + l15)*40 + lq*8);
            s[t] = __builtin_amdgcn_mfma_f32_16x16x32_bf16(afrag, bfrag, zero, 0, 0, 0);
        }
        // P = softmax, write attn fp32 + P bf16 to per-wave LDS
        #pragma unroll
        for (int r = 0; r < 4; ++r) {
            int n_loc = 4*lq + r;
            float* ar = arow + (size_t)n_loc*N + ch*256;
            #pragma unroll
            for (int t = 0; t < 16; ++t) {
                float p = __expf(s[t][r] - mx[r]) * inv[r];
                int m_loc = 16*t + l15;
                ar[m_loc] = p;
                pw[n_loc*264 + m_loc] = bf16_bits(p);
            }
        }
        __asm volatile("" ::: "memory");
        // PV: out[16n][32cl] += P[16n][256m] x V[256m][32cl]
        #pragma unroll
        for (int kk = 0; kk < 8; ++kk) {
            bf16x8 pa = *(const bf16x8*)(pw + l15*264 + kk*32 + lq*8);
            #pragma unroll
            for (int ct = 0; ct < 2; ++ct) {
                bf16x8 vb = *(const bf16x8*)(vs + (16*ct + l15)*264 + kk*32 + lq*8);
                outf[ct] = __builtin_amdgcn_mfma_f32_16x16x32_bf16(pa, vb, outf[ct], 0, 0, 0);
            }
        }
    }

    // write out tile via per-wave LDS transpose for coalesced-ish stores
    __asm volatile("" ::: "memory");
    float* sc = (float*)pw;
    #pragma unroll
    for (int ct = 0; ct < 2; ++ct)
        #pragma unroll
        for (int r = 0; r < 4; ++r)
            sc[(ct*16 + l15)*17 + 4*lq + r] = outf[ct][r];
    __asm volatile("" ::: "memory");
    #pragma unroll
    for (int i = 0; i < 8; ++i) {
        int u = lane + i*64;
        int n_ = u & 15, cl = u >> 4;
        obuf[((size_t)b*C + h*32 + cl)*N + nb*64 + w*16 + n_] = sc[cl*17 + n_];
    }
}

// ---------------------------------------------------------------------------
extern "C" void kernel_launch(void* const* d_in, const int* in_sizes, int n_in,
                              void* d_out, int out_size, void* d_ws, size_t ws_size,
                              hipStream_t stream)
{
    const float* x1  = (const float*)d_in[0];
    const float* x2  = (const float*)d_in[1];
    const float* wq  = (const float*)d_in[2];
    const float* bq  = (const float*)d_in[3];
    const float* wdw = (const float*)d_in[4];
    const float* bdw = (const float*)d_in[5];
    const float* wpw = (const float*)d_in[6];
    const float* bpw = (const float*)d_in[7];
    const float* wk  = (const float*)d_in[8];
    const float* bk  = (const float*)d_in[9];
    const float* wv  = (const float*)d_in[10];
    const float* bv  = (const float*)d_in[11];
    const float* wo  = (const float*)d_in[12];
    const float* bo  = (const float*)d_in[13];

    const size_t PLANE = (size_t)B * C * N;     // 3,145,728 floats
    float* ws      = (float*)d_ws;
    float* qbuf    = ws;                        // q fp32; later reused as v16 space
    float* tbuf    = ws + PLANE;                // dwconv-out, later PV-out
    float* sampled = ws + 2*PLANE;              // sampled fp32; later qT16/kT16 space
    float* kbuf    = ws + 3*PLANE;
    float* vbuf    = ws + 4*PLANE;
    float* coords  = ws + 5*PLANE;              // BG*N float4

    unsigned short* qT16 = (unsigned short*)sampled;                 // 96*1024*32 halves (6.3MB)
    unsigned short* kT16 = (unsigned short*)sampled + (size_t)96*N*32;
    unsigned short* v16  = (unsigned short*)qbuf;                    // after q is dead

    float* ybuf = (float*)d_out;                // (B,C,H,W)
    float* attn = (float*)d_out + PLANE;        // (B,HEADS,N,N)

    gemm384<false><<<dim3(16, 6, 8), 256, 0, stream>>>(wq, bq, x1, nullptr, qbuf);
    dwconv_gelu<<<dim3(4, Cg, BG), 256, 0, stream>>>(qbuf, wdw, bdw, tbuf);
    offset_grid<<<dim3(384), 256, 0, stream>>>(tbuf, wpw, bpw, coords);
    bilin_sample<<<dim3(4, Cg, BG), 256, 0, stream>>>(x2, coords, sampled);
    gemm384<false><<<dim3(16, 6, 8), 256, 0, stream>>>(wk, bk, sampled, nullptr, kbuf);
    gemm384<false><<<dim3(16, 6, 8), 256, 0, stream>>>(wv, bv, sampled, nullptr, vbuf);
    // convert/transpose for MFMA attention (sampled & qbuf are dead after these)
    xpose_bf16<<<dim3(8, 96), 256, 0, stream>>>(qbuf, (unsigned int*)qT16, SCALE);
    xpose_bf16<<<dim3(8, 96), 256, 0, stream>>>(kbuf, (unsigned int*)kT16, 1.0f);
    conv_bf16<<<dim3(1536), 256, 0, stream>>>(vbuf, v16);
    attn_fused<<<dim3(16, 96), 256, 0, stream>>>(qT16, kT16, v16, attn, tbuf);
    gemm384<true><<<dim3(16, 6, 8), 256, 0, stream>>>(wo, bo, tbuf, x1, ybuf);
}

// Round 3
// 214.803 us; speedup vs baseline: 3.4673x; 1.5736x over previous
//
#include <hip/hip_runtime.h>
#include <hip/hip_bf16.h>

static constexpr int B = 8;
static constexpr int C = 384;
static constexpr int H = 32;
static constexpr int W = 32;
static constexpr int N = 1024;      // H*W
static constexpr int Cg = 128;      // C/G
static constexpr int HEADS = 12;
static constexpr int BG = 24;       // B*G
static constexpr float SCALE = 0.17677669529663687f; // hc^-0.5

typedef short bf16x8 __attribute__((ext_vector_type(8)));
typedef float f32x4 __attribute__((ext_vector_type(4)));

__device__ __forceinline__ unsigned short bf16_bits(float x) {
    __hip_bfloat16 h = __float2bfloat16(x);
    return __builtin_bit_cast(unsigned short, h);
}

// ---------------------------------------------------------------------------
// Convert 4 weight matrices (384x384 fp32) to bf16. grid(72,4)
// ---------------------------------------------------------------------------
__global__ __launch_bounds__(256) void wconv_all(const float* __restrict__ w0,
                                                 const float* __restrict__ w1,
                                                 const float* __restrict__ w2,
                                                 const float* __restrict__ w3,
                                                 unsigned short* __restrict__ out)
{
    const int which = blockIdx.y;
    const float* src = (which == 0) ? w0 : (which == 1) ? w1 : (which == 2) ? w2 : w3;
    const int idx = (blockIdx.x * 256 + threadIdx.x) * 8;   // < 147456
    const float4* p = (const float4*)(src + idx);
    float4 f0 = p[0], f1 = p[1];
    uint4 u;
    u.x = (unsigned)bf16_bits(f0.x) | ((unsigned)bf16_bits(f0.y) << 16);
    u.y = (unsigned)bf16_bits(f0.z) | ((unsigned)bf16_bits(f0.w) << 16);
    u.z = (unsigned)bf16_bits(f1.x) | ((unsigned)bf16_bits(f1.y) << 16);
    u.w = (unsigned)bf16_bits(f1.z) | ((unsigned)bf16_bits(f1.w) << 16);
    *(uint4*)(out + (size_t)which * 147456 + idx) = u;
}

// ---------------------------------------------------------------------------
// Transpose+convert x1: fp32 [b][384c][1024n] -> bf16 [b][1024n][384c]
// grid (8 n-chunks of 128, 12 c-chunks of 32, 8 b)
// ---------------------------------------------------------------------------
__global__ __launch_bounds__(256) void xpose_x1(const float* __restrict__ src,
                                                unsigned short* __restrict__ dst)
{
    __shared__ float tile[32][132];
    const int tid = threadIdx.x;
    const int n0 = blockIdx.x * 128, c0 = blockIdx.y * 32, b = blockIdx.z;
    {
        int c = tid >> 3, nq = (tid & 7) * 16;
        const float* sp = src + ((size_t)b*C + c0 + c)*N + n0 + nq;
        #pragma unroll
        for (int i = 0; i < 4; ++i)
            *(float4*)&tile[c][nq + 4*i] = *(const float4*)(sp + 4*i);
    }
    __syncthreads();
    {
        int n = tid >> 1, cb = (tid & 1) * 16;
        unsigned short* dp = dst + ((size_t)b*N + n0 + n)*C + c0 + cb;
        #pragma unroll
        for (int half = 0; half < 2; ++half) {
            bf16x8 v;
            #pragma unroll
            for (int j = 0; j < 8; ++j)
                v[j] = (short)bf16_bits(tile[cb + half*8 + j][n]);
            *(bf16x8*)(dp + half*8) = v;
        }
    }
}

// ---------------------------------------------------------------------------
// Token-major bf16 -> spatial fp32 (for the offset path).
// grid (8 n-chunks of 128, 12 c-chunks of 32, 8 b)
// ---------------------------------------------------------------------------
__global__ __launch_bounds__(256) void tok2spat(const unsigned short* __restrict__ src,
                                                float* __restrict__ dst)
{
    __shared__ float tile[32][132];
    const int tid = threadIdx.x;
    const int n0 = blockIdx.x * 128, c0 = blockIdx.y * 32, b = blockIdx.z;
    {
        int n = tid >> 1, cb = (tid & 1) * 16;
        const unsigned short* sp = src + ((size_t)b*N + n0 + n)*C + c0 + cb;
        #pragma unroll
        for (int half = 0; half < 2; ++half) {
            bf16x8 v = *(const bf16x8*)(sp + half*8);
            #pragma unroll
            for (int j = 0; j < 8; ++j) {
                unsigned int u = ((unsigned int)(unsigned short)v[j]) << 16;
                tile[cb + half*8 + j][n] = __builtin_bit_cast(float, u);
            }
        }
    }
    __syncthreads();
    {
        int c = tid >> 3, nq = (tid & 7) * 16;
        float* dp = dst + ((size_t)b*C + c0 + c)*N + n0 + nq;
        #pragma unroll
        for (int i = 0; i < 4; ++i)
            *(float4*)(dp + 4*i) = *(const float4*)&tile[c][nq + 4*i];
    }
}

// ---------------------------------------------------------------------------
// MFMA projection: out[n][o] = sum_c XT[n][c] * Wb[o][c] (+bias)(*scale)
// XT: bf16 token-major [b][1024][384]. Wb: bf16 [384][384].
// MODE 0: out bf16 token-major [b][1024][384]
// MODE 1: out bf16 spatial [b][384][1024]
// MODE 2: out fp32 spatial [b][384][1024] + res
// grid (16 n-tiles, 6 o-tiles, 8 b), 256 threads (4 waves, 32x32 quadrant each)
// ---------------------------------------------------------------------------
template<int MODE>
__global__ __launch_bounds__(256) void proj_mfma(const unsigned short* __restrict__ XT,
                                                 const unsigned short* __restrict__ Wb,
                                                 const float* __restrict__ bias,
                                                 const float* __restrict__ res,
                                                 void* __restrict__ out,
                                                 float scale)
{
    __shared__ __align__(16) char smem[64*72*2*2];   // 18,432 B
    unsigned short* sA = (unsigned short*)smem;      // [64n][72c]
    unsigned short* sB = sA + 64*72;                 // [64o][72c]
    float* ep = (float*)smem;                        // epilogue [64n][65o]

    const int tid = threadIdx.x;
    const int lane = tid & 63, w = tid >> 6;
    const int l15 = lane & 15, lq = lane >> 4;
    const int n0 = blockIdx.x * 64, o0 = blockIdx.y * 64, b = blockIdx.z;
    const int qn = (w & 1) * 32, qo = (w >> 1) * 32;

    const unsigned short* xg = XT + ((size_t)b*N + n0)*C;
    const unsigned short* wg = Wb + (size_t)o0*C;

    const f32x4 zero = {0.f, 0.f, 0.f, 0.f};
    f32x4 a00 = zero, a01 = zero, a10 = zero, a11 = zero;

    const int r = tid >> 2, c8 = (tid & 3) * 8;
    for (int c0 = 0; c0 < C; c0 += 64) {
        __syncthreads();
        *(bf16x8*)(sA + r*72 + c8)      = *(const bf16x8*)(xg + (size_t)r*C + c0 + c8);
        *(bf16x8*)(sA + r*72 + c8 + 32) = *(const bf16x8*)(xg + (size_t)r*C + c0 + c8 + 32);
        *(bf16x8*)(sB + r*72 + c8)      = *(const bf16x8*)(wg + (size_t)r*C + c0 + c8);
        *(bf16x8*)(sB + r*72 + c8 + 32) = *(const bf16x8*)(wg + (size_t)r*C + c0 + c8 + 32);
        __syncthreads();
        #pragma unroll
        for (int ks = 0; ks < 2; ++ks) {
            bf16x8 fa0 = *(const bf16x8*)(sA + (qn + l15)*72      + ks*32 + lq*8);
            bf16x8 fa1 = *(const bf16x8*)(sA + (qn + 16 + l15)*72 + ks*32 + lq*8);
            bf16x8 fb0 = *(const bf16x8*)(sB + (qo + l15)*72      + ks*32 + lq*8);
            bf16x8 fb1 = *(const bf16x8*)(sB + (qo + 16 + l15)*72 + ks*32 + lq*8);
            a00 = __builtin_amdgcn_mfma_f32_16x16x32_bf16(fa0, fb0, a00, 0, 0, 0);
            a01 = __builtin_amdgcn_mfma_f32_16x16x32_bf16(fa0, fb1, a01, 0, 0, 0);
            a10 = __builtin_amdgcn_mfma_f32_16x16x32_bf16(fa1, fb0, a10, 0, 0, 0);
            a11 = __builtin_amdgcn_mfma_f32_16x16x32_bf16(fa1, fb1, a11, 0, 0, 0);
        }
    }
    __syncthreads();
    #pragma unroll
    for (int rr = 0; rr < 4; ++rr) {
        int nr0 = qn + 4*lq + rr, nr1 = qn + 16 + 4*lq + rr;
        ep[nr0*65 + qo + l15]      = a00[rr];
        ep[nr0*65 + qo + 16 + l15] = a01[rr];
        ep[nr1*65 + qo + l15]      = a10[rr];
        ep[nr1*65 + qo + 16 + l15] = a11[rr];
    }
    __syncthreads();

    if constexpr (MODE == 0) {
        int n = tid >> 2, ch = tid & 3;
        unsigned short* op = (unsigned short*)out + ((size_t)b*N + n0 + n)*C + o0;
        #pragma unroll
        for (int half = 0; half < 2; ++half) {
            int ob = ch*8 + half*32;
            bf16x8 v;
            #pragma unroll
            for (int j = 0; j < 8; ++j)
                v[j] = (short)bf16_bits((ep[n*65 + ob + j] + bias[o0 + ob + j]) * scale);
            *(bf16x8*)(op + ob) = v;
        }
    } else if constexpr (MODE == 1) {
        int o = tid >> 2, nc = (tid & 3) * 16;
        float bz = bias[o0 + o];
        unsigned short* op = (unsigned short*)out + ((size_t)b*C + o0 + o)*N + n0 + nc;
        #pragma unroll
        for (int half = 0; half < 2; ++half) {
            bf16x8 v;
            #pragma unroll
            for (int j = 0; j < 8; ++j)
                v[j] = (short)bf16_bits((ep[(nc + half*8 + j)*65 + o] + bz) * scale);
            *(bf16x8*)(op + half*8) = v;
        }
    } else {
        int o = tid >> 2, nc = (tid & 3) * 16;
        float bz = bias[o0 + o];
        size_t base = ((size_t)b*C + o0 + o)*N + n0 + nc;
        #pragma unroll
        for (int i = 0; i < 4; ++i) {
            float4 rv = *(const float4*)(res + base + 4*i);
            float4 v;
            v.x = ep[(nc + 4*i + 0)*65 + o] + bz + rv.x;
            v.y = ep[(nc + 4*i + 1)*65 + o] + bz + rv.y;
            v.z = ep[(nc + 4*i + 2)*65 + o] + bz + rv.z;
            v.w = ep[(nc + 4*i + 3)*65 + o] + bz + rv.w;
            *(float4*)((float*)out + base + 4*i) = v;
        }
    }
}

// ---------------------------------------------------------------------------
// Depthwise 5x5 conv (SAME) + bias + tanh GELU. Reads fp32 spatial q.
// ---------------------------------------------------------------------------
__global__ __launch_bounds__(256) void dwconv_gelu(const float* __restrict__ q,
                                                   const float* __restrict__ wdw,
                                                   const float* __restrict__ bdw,
                                                   float* __restrict__ t)
{
    const int n = blockIdx.x * 256 + threadIdx.x;
    const int c = blockIdx.y, bg = blockIdx.z;
    const int y = n >> 5, x = n & 31;
    const float* qc = q + ((size_t)bg*Cg + c)*N;
    const float* wc = wdw + c*25;
    float acc = bdw[c];
    #pragma unroll
    for (int ky = 0; ky < 5; ++ky) {
        int yy = y + ky - 2;
        if (yy < 0 || yy >= H) continue;
        #pragma unroll
        for (int kx = 0; kx < 5; ++kx) {
            int xx = x + kx - 2;
            if (xx < 0 || xx >= W) continue;
            acc += wc[ky*5 + kx] * qc[yy*W + xx];
        }
    }
    float u = acc;
    float g = 0.5f*u*(1.0f + tanhf(0.7978845608028654f*(u + 0.044715f*u*u*u)));
    t[((size_t)bg*Cg + c)*N + n] = g;
}

// ---------------------------------------------------------------------------
// Pointwise conv (2 x Cg) + tanh -> clipped grid -> bilinear coords. grid(384)
// ---------------------------------------------------------------------------
__global__ __launch_bounds__(256) void offset_grid(const float* __restrict__ t,
                                                   const float* __restrict__ wpw,
                                                   const float* __restrict__ bpw,
                                                   float* __restrict__ coords)
{
    __shared__ float r0[4][64], r1[4][64];
    const int bx = blockIdx.x;
    const int bg = bx >> 4, n0 = (bx & 15) * 64;
    const int nl = threadIdx.x & 63, cq = threadIdx.x >> 6;
    const float* tb = t + ((size_t)bg*Cg + cq*32)*N + n0 + nl;
    float a0 = 0.f, a1 = 0.f;
    #pragma unroll 8
    for (int i = 0; i < 32; ++i) {
        float tv = tb[(size_t)i*N];
        a0 += wpw[cq*32 + i] * tv;
        a1 += wpw[Cg + cq*32 + i] * tv;
    }
    r0[cq][nl] = a0; r1[cq][nl] = a1;
    __syncthreads();
    if (threadIdx.x < 64) {
        int n = n0 + nl;
        a0 = bpw[0] + r0[0][nl] + r0[1][nl] + r0[2][nl] + r0[3][nl];
        a1 = bpw[1] + r1[0][nl] + r1[1][nl] + r1[2][nl] + r1[3][nl];
        const int x = n & 31, y = n >> 5;
        float dx = tanhf(a0) * (2.0f / W);
        float dy = tanhf(a1) * (2.0f / H);
        float rx = (x + 0.5f) / W * 2.0f - 1.0f;
        float ry = (y + 0.5f) / H * 2.0f - 1.0f;
        float px = fminf(fmaxf(rx + dx, -1.0f), 1.0f);
        float py = fminf(fmaxf(ry + dy, -1.0f), 1.0f);
        float gx = (px + 1.0f) * 0.5f * (W - 1);
        float gy = (py + 1.0f) * 0.5f * (H - 1);
        float x0 = floorf(gx), y0 = floorf(gy);
        float wx1 = gx - x0, wy1 = gy - y0;
        x0 = fminf(fmaxf(x0, 0.0f), (float)(W - 1));
        y0 = fminf(fmaxf(y0, 0.0f), (float)(H - 1));
        ((float4*)coords)[bg*N + n] = make_float4(x0, y0, wx1, wy1);
    }
}

// ---------------------------------------------------------------------------
// Bilinear gather of x2 -> token-major bf16 sampledT [b][1024n][384c].
// grid (16 n-chunks of 64, 24 bg); threads: 64n x 4 c-quarters.
// ---------------------------------------------------------------------------
__global__ __launch_bounds__(256) void bilin_sample(const float* __restrict__ x2,
                                                    const float* __restrict__ coords,
                                                    unsigned short* __restrict__ sampT)
{
    __shared__ unsigned short st[64][130];
    const int tid = threadIdx.x;
    const int n0 = blockIdx.x * 64, bg = blockIdx.y;
    const int b = bg / 3, g = bg % 3;
    const int nl = tid & 63, cq = tid >> 6;
    float4 c4 = ((const float4*)coords)[bg*N + n0 + nl];
    int x0 = (int)c4.x, y0 = (int)c4.y;
    float wx1 = c4.z, wy1 = c4.w;
    int x1 = min(x0 + 1, W - 1), y1 = min(y0 + 1, H - 1);
    float wx0 = 1.0f - wx1, wy0 = 1.0f - wy1;
    const float* base = x2 + (size_t)bg*Cg*N;
    #pragma unroll 4
    for (int i = 0; i < 32; ++i) {
        int c = cq*32 + i;
        const float* img = base + (size_t)c*N;
        float v00 = img[y0*W + x0], v01 = img[y0*W + x1];
        float v10 = img[y1*W + x0], v11 = img[y1*W + x1];
        float v = wy0*(wx0*v00 + wx1*v01) + wy1*(wx0*v10 + wx1*v11);
        st[nl][c] = bf16_bits(v);
    }
    __syncthreads();
    {
        int n = tid >> 2;
        unsigned short* dp = sampT + ((size_t)b*N + n0 + n)*C + g*Cg;
        #pragma unroll
        for (int i = 0; i < 4; ++i) {
            int c8 = ((tid & 3) + 4*i) * 8;
            *(bf16x8*)(dp + c8) = *(const bf16x8*)&st[n][c8];
        }
    }
}

// ---------------------------------------------------------------------------
// Fused attention. Q16/K16 token-major bf16 [b][1024][384] (K pre-scaled),
// V16 spatial bf16 [b][384][1024]. attn fp32 out; OT token-major bf16 out.
// grid (16, 96)
// ---------------------------------------------------------------------------
__global__ __launch_bounds__(256) void attn_fused(const unsigned short* __restrict__ Q16,
                                                  const unsigned short* __restrict__ K16,
                                                  const unsigned short* __restrict__ V16,
                                                  float* __restrict__ attn,
                                                  unsigned short* __restrict__ OT)
{
    __shared__ __align__(16) unsigned short qs[64*40];     //  5,120 B
    __shared__ __align__(16) unsigned short ks[256*40];    // 20,480 B
    __shared__ __align__(16) unsigned short vs[32*264];    // 16,896 B
    __shared__ __align__(16) unsigned short ps[4][16*264]; // 33,792 B

    const int tid = threadIdx.x;
    const int lane = tid & 63, w = tid >> 6;
    const int l15 = lane & 15, lq = lane >> 4;
    const int nb = blockIdx.x, bh = blockIdx.y;
    const int b = bh / HEADS, h = bh - b*HEADS;

    const unsigned short* qg = Q16 + ((size_t)b*N + nb*64)*C + h*32;
    const unsigned short* kg = K16 + (size_t)b*N*C + h*32;
    const unsigned short* vg = V16 + ((size_t)b*C + h*32)*N;

    {
        int rr = tid >> 2, c8 = (tid & 3) * 8;
        *(bf16x8*)(qs + rr*40 + c8) = *(const bf16x8*)(qg + (size_t)rr*C + c8);
    }
    __syncthreads();
    const bf16x8 afrag = *(const bf16x8*)(qs + (w*16 + l15)*40 + lq*8);

    float mx[4] = {-3.4e38f, -3.4e38f, -3.4e38f, -3.4e38f};
    float sm[4] = {0.f, 0.f, 0.f, 0.f};
    f32x4 s[16];
    const f32x4 zero = {0.f, 0.f, 0.f, 0.f};

    // ------------------ PASS 1: stats ------------------
    for (int ch = 0; ch < 4; ++ch) {
        __syncthreads();
        #pragma unroll
        for (int i = 0; i < 4; ++i) {
            int m = i*64 + (tid >> 2), c8 = (tid & 3) * 8;
            *(bf16x8*)(ks + m*40 + c8) = *(const bf16x8*)(kg + ((size_t)ch*256 + m)*C + c8);
        }
        __syncthreads();
        #pragma unroll
        for (int t = 0; t < 16; ++t) {
            bf16x8 bfrag = *(const bf16x8*)(ks + (16*t + l15)*40 + lq*8);
            s[t] = __builtin_amdgcn_mfma_f32_16x16x32_bf16(afrag, bfrag, zero, 0, 0, 0);
        }
        #pragma unroll
        for (int r = 0; r < 4; ++r) {
            float cm = s[0][r];
            #pragma unroll
            for (int t = 1; t < 16; ++t) cm = fmaxf(cm, s[t][r]);
            cm = fmaxf(cm, __shfl_xor(cm, 1));
            cm = fmaxf(cm, __shfl_xor(cm, 2));
            cm = fmaxf(cm, __shfl_xor(cm, 4));
            cm = fmaxf(cm, __shfl_xor(cm, 8));
            float nm = fmaxf(mx[r], cm);
            float corr = __expf(mx[r] - nm);
            float es = 0.f;
            #pragma unroll
            for (int t = 0; t < 16; ++t) es += __expf(s[t][r] - nm);
            es += __shfl_xor(es, 1);
            es += __shfl_xor(es, 2);
            es += __shfl_xor(es, 4);
            es += __shfl_xor(es, 8);
            sm[r] = sm[r]*corr + es;
            mx[r] = nm;
        }
    }
    float inv[4];
    #pragma unroll
    for (int r = 0; r < 4; ++r) inv[r] = 1.0f / sm[r];

    // ------------------ PASS 2: P write + PV ------------------
    f32x4 outf[2] = {zero, zero};
    unsigned short* pw = ps[w];
    float* arow = attn + ((size_t)bh*N + (size_t)nb*64 + w*16)*N;

    for (int ch = 0; ch < 4; ++ch) {
        __syncthreads();
        #pragma unroll
        for (int i = 0; i < 4; ++i) {
            int m = i*64 + (tid >> 2), c8 = (tid & 3) * 8;
            *(bf16x8*)(ks + m*40 + c8) = *(const bf16x8*)(kg + ((size_t)ch*256 + m)*C + c8);
        }
        #pragma unroll
        for (int i = 0; i < 4; ++i) {
            int u = tid + i*256;
            int cl = u >> 5, gg = u & 31;
            *(bf16x8*)(vs + cl*264 + gg*8) = *(const bf16x8*)(vg + (size_t)cl*N + ch*256 + gg*8);
        }
        __syncthreads();
        #pragma unroll
        for (int t = 0; t < 16; ++t) {
            bf16x8 bfrag = *(const bf16x8*)(ks + (16*t + l15)*40 + lq*8);
            s[t] = __builtin_amdgcn_mfma_f32_16x16x32_bf16(afrag, bfrag, zero, 0, 0, 0);
        }
        #pragma unroll
        for (int r = 0; r < 4; ++r) {
            int n_loc = 4*lq + r;
            float* ar = arow + (size_t)n_loc*N + ch*256;
            #pragma unroll
            for (int t = 0; t < 16; ++t) {
                float p = __expf(s[t][r] - mx[r]) * inv[r];
                int m_loc = 16*t + l15;
                ar[m_loc] = p;
                pw[n_loc*264 + m_loc] = bf16_bits(p);
            }
        }
        __asm volatile("" ::: "memory");
        #pragma unroll
        for (int kk = 0; kk < 8; ++kk) {
            bf16x8 pa = *(const bf16x8*)(pw + l15*264 + kk*32 + lq*8);
            #pragma unroll
            for (int ct = 0; ct < 2; ++ct) {
                bf16x8 vb = *(const bf16x8*)(vs + (16*ct + l15)*264 + kk*32 + lq*8);
                outf[ct] = __builtin_amdgcn_mfma_f32_16x16x32_bf16(pa, vb, outf[ct], 0, 0, 0);
            }
        }
    }

    // write PV tile token-major bf16 via per-wave LDS repack
    __asm volatile("" ::: "memory");
    float* sc = (float*)pw;   // [16n][33c]
    #pragma unroll
    for (int ct = 0; ct < 2; ++ct)
        #pragma unroll
        for (int r = 0; r < 4; ++r)
            sc[(4*lq + r)*33 + ct*16 + l15] = outf[ct][r];
    __asm volatile("" ::: "memory");
    {
        int n = lane >> 2, c8 = (lane & 3) * 8;
        bf16x8 v;
        #pragma unroll
        for (int j = 0; j < 8; ++j)
            v[j] = (short)bf16_bits(sc[n*33 + c8 + j]);
        *(bf16x8*)(OT + ((size_t)b*N + nb*64 + w*16 + n)*C + h*32 + c8) = v;
    }
}

// ---------------------------------------------------------------------------
extern "C" void kernel_launch(void* const* d_in, const int* in_sizes, int n_in,
                              void* d_out, int out_size, void* d_ws, size_t ws_size,
                              hipStream_t stream)
{
    const float* x1  = (const float*)d_in[0];
    const float* x2  = (const float*)d_in[1];
    const float* wq  = (const float*)d_in[2];
    const float* bq  = (const float*)d_in[3];
    const float* wdw = (const float*)d_in[4];
    const float* bdw = (const float*)d_in[5];
    const float* wpw = (const float*)d_in[6];
    const float* bpw = (const float*)d_in[7];
    const float* wk  = (const float*)d_in[8];
    const float* bk  = (const float*)d_in[9];
    const float* wv  = (const float*)d_in[10];
    const float* bv  = (const float*)d_in[11];
    const float* wo  = (const float*)d_in[12];
    const float* bo  = (const float*)d_in[13];

    const size_t P = (size_t)B * C * N;          // 3,145,728 floats
    float* ws = (float*)d_ws;
    unsigned short* x1T   = (unsigned short*)ws;             // 0.5P (bf16), reused as OT
    unsigned short* OT    = x1T;
    unsigned short* Q16   = (unsigned short*)(ws + P/2);     // 0.5P
    float*          qspat = ws + P;                          // 1P fp32
    float*          tbuf  = ws + 2*P;                        // 1P fp32
    unsigned short* sampT = (unsigned short*)(ws + 3*P);     // 0.5P
    unsigned short* K16   = (unsigned short*)(ws + 3*P + P/2);
    unsigned short* V16   = (unsigned short*)(ws + 4*P);     // 0.5P
    float*          coords= ws + 4*P + P/2;                  // 98,304 floats
    unsigned short* w16   = (unsigned short*)(ws + 4*P + P/2 + 98304);
    unsigned short* w16q = w16;
    unsigned short* w16k = w16 + 147456;
    unsigned short* w16v = w16 + 2*147456;
    unsigned short* w16o = w16 + 3*147456;

    float* ybuf = (float*)d_out;                 // (B,C,H,W)
    float* attn = (float*)d_out + P;             // (B,HEADS,N,N)

    wconv_all<<<dim3(72, 4), 256, 0, stream>>>(wq, wk, wv, wo, w16);
    xpose_x1<<<dim3(8, 12, 8), 256, 0, stream>>>(x1, x1T);
    proj_mfma<0><<<dim3(16, 6, 8), 256, 0, stream>>>(x1T, w16q, bq, nullptr, Q16, 1.0f);
    tok2spat<<<dim3(8, 12, 8), 256, 0, stream>>>(Q16, qspat);
    dwconv_gelu<<<dim3(4, Cg, BG), 256, 0, stream>>>(qspat, wdw, bdw, tbuf);
    offset_grid<<<dim3(384), 256, 0, stream>>>(tbuf, wpw, bpw, coords);
    bilin_sample<<<dim3(16, BG), 256, 0, stream>>>(x2, coords, sampT);
    proj_mfma<0><<<dim3(16, 6, 8), 256, 0, stream>>>(sampT, w16k, bk, nullptr, K16, SCALE);
    proj_mfma<1><<<dim3(16, 6, 8), 256, 0, stream>>>(sampT, w16v, bv, nullptr, V16, 1.0f);
    attn_fused<<<dim3(16, 96), 256, 0, stream>>>(Q16, K16, V16, attn, OT);
    proj_mfma<2><<<dim3(16, 6, 8), 256, 0, stream>>>(OT, w16o, bo, x1, ybuf, 1.0f);
}